// Round 5
// baseline (110.645 us; speedup 1.0000x reference)
//
#include <hip/hip_runtime.h>

// BuildCombinationsDim2: out[b,t,j] = x[b,t, idx[j]] where idx is the
// flattened list of k=2 combinations of F=32 features (lexicographic).
// ncr = 2*C(32,2) = 992. Pure gather along last axis; write-BW-bound.
// R5: few-stream persistent layout — 512 blocks (2/CU), each owning a
// contiguous 1 MB output span (16 x 16-row tiles), double-buffered LDS
// staging so the nt-store stream never stalls. Mimics the fill kernel's
// low-occupancy / long-contiguous-stream profile (6.9 TB/s demonstrated).

#define FDIM 32
#define NCR 992            // k * C(F,2)
#define G_PER_ROW 248      // NCR / 4 float4 groups per row
#define TROWS 16           // rows per LDS tile
#define BLOCK 256
#define GRID 512           // 2 blocks/CU -> ~512 concurrent write streams

typedef float f32x4 __attribute__((ext_vector_type(4)));
typedef float f32x2 __attribute__((ext_vector_type(2)));

__global__ __launch_bounds__(BLOCK)
void comb_gather_kernel(const float* __restrict__ x,
                        float* __restrict__ out,
                        int nrows) {
    __shared__ float lds[2][TROWS * FDIM];   // 2 x 2 KB double buffer

    const int tid = threadIdx.x;
    const int tiles_total = (nrows + TROWS - 1) / TROWS;
    const int tpb = (tiles_total + (int)gridDim.x - 1) / (int)gridDim.x;
    const int t0  = blockIdx.x * tpb;
    const int t1  = (t0 + tpb < tiles_total) ? (t0 + tpb) : tiles_total;
    if (t0 >= t1) return;

    // Gather indices for this thread's float4 group (once per kernel).
    // Column j = 4g+u -> combination c = 2g + (u>>1), position j&1.
    // Closed-form inversion of start(i) = i*(63-i)/2 with +-1 fixup.
    int feat[4];
    {
        const int g  = (tid < G_PER_ROW) ? tid : 0;
        const int c0 = 2 * g;
        float s = sqrtf(3969.0f - 8.0f * (float)c0);
        int i0 = (int)((63.0f - s) * 0.5f);
        if (i0 < 0) i0 = 0;
        int st0  = (i0 * (63 - i0)) >> 1;
        int stn0 = ((i0 + 1) * (62 - i0)) >> 1;
        if (stn0 <= c0) { i0++; st0 = stn0; stn0 = ((i0 + 1) * (62 - i0)) >> 1; }
        else if (st0 > c0) { i0--; stn0 = st0; st0 = (i0 * (63 - i0)) >> 1; }
        feat[0] = i0;
        feat[1] = c0 - st0 + i0 + 1;
        const int c1 = c0 + 1;
        int i1 = i0, st1 = st0;
        if (stn0 <= c1) { i1 = i0 + 1; st1 = stn0; }
        feat[2] = i1;
        feat[3] = c1 - st1 + i1 + 1;
    }

    const size_t xtot = (size_t)nrows * FDIM;

    // Per-thread f32x2 load of tile t's 512-float slab (guarded for tail).
    auto load_tile = [&](int t) -> f32x2 {
        size_t base = (size_t)t * (TROWS * FDIM) + 2 * tid;
        f32x2 v; v.x = 0.f; v.y = 0.f;
        if (base + 1 < xtot) v = *reinterpret_cast<const f32x2*>(x + base);
        else if (base < xtot) v.x = x[base];
        return v;
    };

    // Prologue: stage tile t0 into buffer 0.
    {
        f32x2 cur = load_tile(t0);
        reinterpret_cast<f32x2*>(lds[0])[tid] = cur;
    }
    __syncthreads();

    int buf = 0;
    for (int t = t0; t < t1; ++t) {
        // Issue next tile's global load BEFORE the stores (latency hides
        // under the 16 nt-stores); LDS-write it after, just before barrier.
        f32x2 nxt;
        const bool havenext = (t + 1 < t1);
        if (havenext) nxt = load_tile(t + 1);

        if (tid < G_PER_ROW) {
            const int g = tid;
            const float* L = lds[buf];
            const int rbeg = t * TROWS;
            const int rcnt = (nrows - rbeg < TROWS) ? (nrows - rbeg) : TROWS;
            f32x4* outp = reinterpret_cast<f32x4*>(out + (size_t)rbeg * NCR) + g;
            if (rcnt == TROWS) {
                #pragma unroll
                for (int r = 0; r < TROWS; ++r) {
                    const float* rowp = L + r * FDIM;
                    f32x4 v;
                    v.x = rowp[feat[0]];
                    v.y = rowp[feat[1]];
                    v.z = rowp[feat[2]];
                    v.w = rowp[feat[3]];
                    __builtin_nontemporal_store(v, outp);   // stream past L2
                    outp += NCR / 4;
                }
            } else {
                for (int r = 0; r < rcnt; ++r) {
                    const float* rowp = L + r * FDIM;
                    f32x4 v;
                    v.x = rowp[feat[0]];
                    v.y = rowp[feat[1]];
                    v.z = rowp[feat[2]];
                    v.w = rowp[feat[3]];
                    __builtin_nontemporal_store(v, outp);
                    outp += NCR / 4;
                }
            }
        }

        if (havenext)
            reinterpret_cast<f32x2*>(lds[buf ^ 1])[tid] = nxt;
        __syncthreads();
        buf ^= 1;
    }
}

extern "C" void kernel_launch(void* const* d_in, const int* in_sizes, int n_in,
                              void* d_out, int out_size, void* d_ws, size_t ws_size,
                              hipStream_t stream) {
    const float* x  = (const float*)d_in[0];
    float* out      = (float*)d_out;
    int nrows = in_sizes[0] / FDIM;                       // 32*4096 = 131072
    hipLaunchKernelGGL(comb_gather_kernel, dim3(GRID), dim3(BLOCK), 0, stream,
                       x, out, nrows);
}

// Round 6
// 103.646 us; speedup vs baseline: 1.0675x; 1.0675x over previous
//
#include <hip/hip_runtime.h>

// BuildCombinationsDim2: out[b,t,j] = x[b,t, idx[j]] where idx is the
// flattened list of k=2 combinations of F=32 features (lexicographic).
// ncr = 2*C(32,2) = 992. Pure gather along last axis; write-BW-bound.
// R6: no-LDS, no-barrier direct gather. Input row (128 B) is L1-resident
// with ~31x intra-block reuse; each thread does 4 cached scalar loads +
// 1 nt float4 store per row, 16 independent rows unrolled -> compiler
// software-pipelines. Structurally mimics the 6.9 TB/s fill kernel
// (pure store stream, no barriers, no LDS dependency chain).

#define FDIM 32
#define NCR 992            // k * C(F,2)
#define G_PER_ROW 248      // NCR / 4 float4 groups per row
#define TROWS 16           // rows per block
#define BLOCK 256

typedef float f32x4 __attribute__((ext_vector_type(4)));

__global__ __launch_bounds__(BLOCK)
void comb_gather_kernel(const float* __restrict__ x,
                        float* __restrict__ out,
                        int nrows) {
    const int g    = threadIdx.x;
    const int row0 = blockIdx.x * TROWS;
    if (g >= G_PER_ROW) return;

    // Thread g owns output float4 group g: columns j = 4g..4g+3.
    // j -> combination c = 2g + (u>>1), position j&1. Closed-form
    // inversion of start(i) = i*(63-i)/2 with +-1 integer fixup.
    int feat[4];
    {
        const int c0 = 2 * g;
        float s = sqrtf(3969.0f - 8.0f * (float)c0);
        int i0 = (int)((63.0f - s) * 0.5f);
        if (i0 < 0) i0 = 0;
        int st0  = (i0 * (63 - i0)) >> 1;
        int stn0 = ((i0 + 1) * (62 - i0)) >> 1;
        if (stn0 <= c0) { i0++; st0 = stn0; stn0 = ((i0 + 1) * (62 - i0)) >> 1; }
        else if (st0 > c0) { i0--; stn0 = st0; st0 = (i0 * (63 - i0)) >> 1; }
        feat[0] = i0;
        feat[1] = c0 - st0 + i0 + 1;
        const int c1 = c0 + 1;
        int i1 = i0, st1 = st0;
        if (stn0 <= c1) { i1 = i0 + 1; st1 = stn0; }
        feat[2] = i1;
        feat[3] = c1 - st1 + i1 + 1;
    }

    const float* rp = x + (size_t)row0 * FDIM;
    f32x4* outp = reinterpret_cast<f32x4*>(out + (size_t)row0 * NCR) + g;

    if (row0 + TROWS <= nrows) {
        // 16 independent gather+store iterations; no barriers, no LDS.
        #pragma unroll
        for (int r = 0; r < TROWS; ++r) {
            const float* rowp = rp + r * FDIM;   // 128 B row, L1-hit after 1st touch
            f32x4 v;
            v.x = rowp[feat[0]];
            v.y = rowp[feat[1]];
            v.z = rowp[feat[2]];
            v.w = rowp[feat[3]];
            __builtin_nontemporal_store(v, outp);   // stream past L2
            outp += NCR / 4;
        }
    } else {
        for (int r = 0; r < nrows - row0; ++r) {
            const float* rowp = rp + r * FDIM;
            f32x4 v;
            v.x = rowp[feat[0]];
            v.y = rowp[feat[1]];
            v.z = rowp[feat[2]];
            v.w = rowp[feat[3]];
            __builtin_nontemporal_store(v, outp);
            outp += NCR / 4;
        }
    }
}

extern "C" void kernel_launch(void* const* d_in, const int* in_sizes, int n_in,
                              void* d_out, int out_size, void* d_ws, size_t ws_size,
                              hipStream_t stream) {
    const float* x  = (const float*)d_in[0];
    float* out      = (float*)d_out;
    int nrows = in_sizes[0] / FDIM;                       // 32*4096 = 131072
    int grid  = (nrows + TROWS - 1) / TROWS;              // 8192
    hipLaunchKernelGGL(comb_gather_kernel, dim3(grid), dim3(BLOCK), 0, stream,
                       x, out, nrows);
}

// Round 7
// 103.499 us; speedup vs baseline: 1.0690x; 1.0014x over previous
//
#include <hip/hip_runtime.h>

// BuildCombinationsDim2: out[b,t,j] = x[b,t, idx[j]] where idx is the
// flattened list of k=2 combinations of F=32 features (lexicographic).
// ncr = 2*C(32,2) = 992. Pure gather along last axis; write-BW-bound.
// R7: coordinated moving-front writes. Grid = 2048 blocks (exact chip
// residency); block b writes rows b, b+2048, b+4096, ... so the chip's
// instantaneous store window is one contiguous ~8 MB front marching
// through the 520 MB output (fill-kernel profile). Prologue pulls each
// block's 64 input rows (8 KB) into L1/L2 in one wave instruction ->
// steady state is a pure write stream (no HBM read turnarounds).

#define FDIM 32
#define NCR 992            // k * C(F,2)
#define G_PER_ROW 248      // NCR / 4 float4 groups per row
#define BLOCK 256
#define GRID 2048          // = 8 blocks/CU x 256 CU residency

typedef float f32x4 __attribute__((ext_vector_type(4)));

__global__ __launch_bounds__(BLOCK, 8)
void comb_gather_kernel(const float* __restrict__ x,
                        float* __restrict__ out,
                        int nrows) {
    const int tid = threadIdx.x;
    const int b   = blockIdx.x;

    // Prologue: warm this block's rows (b + r*GRID) into L1/L2.
    // One 128 B row == one cache line; 64 lanes touch 64 rows at once.
    {
        const int r = tid;  // lane r warms row for iteration r
        size_t row = (size_t)b + (size_t)r * GRID;
        if (tid < 64 && row < (size_t)nrows) {
            float w = x[row * FDIM];
            asm volatile("" :: "v"(w));   // keep the touch alive
        }
    }

    if (tid >= G_PER_ROW) return;

    // Thread owns output float4 group tid: columns j = 4*tid .. 4*tid+3.
    // j -> combination c = 2*tid + (u>>1), position j&1. Closed-form
    // inversion of start(i) = i*(63-i)/2 with +-1 integer fixup.
    int feat[4];
    {
        const int c0 = 2 * tid;
        float s = sqrtf(3969.0f - 8.0f * (float)c0);
        int i0 = (int)((63.0f - s) * 0.5f);
        if (i0 < 0) i0 = 0;
        int st0  = (i0 * (63 - i0)) >> 1;
        int stn0 = ((i0 + 1) * (62 - i0)) >> 1;
        if (stn0 <= c0) { i0++; st0 = stn0; stn0 = ((i0 + 1) * (62 - i0)) >> 1; }
        else if (st0 > c0) { i0--; stn0 = st0; st0 = (i0 * (63 - i0)) >> 1; }
        feat[0] = i0;
        feat[1] = c0 - st0 + i0 + 1;
        const int c1 = c0 + 1;
        int i1 = i0, st1 = st0;
        if (stn0 <= c1) { i1 = i0 + 1; st1 = stn0; }
        feat[2] = i1;
        feat[3] = c1 - st1 + i1 + 1;
    }

    const float* rowp = x + (size_t)b * FDIM;
    f32x4*       outp = reinterpret_cast<f32x4*>(out + (size_t)b * NCR) + tid;
    const size_t xstep = (size_t)GRID * FDIM;        // floats per iteration
    const size_t ostep = (size_t)GRID * (NCR / 4);   // f32x4 groups per iter

    const int iters = (nrows - b + GRID - 1) / GRID; // 64 for 131072 rows

    #pragma unroll 4
    for (int r = 0; r < iters; ++r) {
        f32x4 v;
        v.x = rowp[feat[0]];   // L1-hit after prologue warm
        v.y = rowp[feat[1]];
        v.z = rowp[feat[2]];
        v.w = rowp[feat[3]];
        __builtin_nontemporal_store(v, outp);   // stream past L2
        rowp += xstep;
        outp += ostep;
    }
}

extern "C" void kernel_launch(void* const* d_in, const int* in_sizes, int n_in,
                              void* d_out, int out_size, void* d_ws, size_t ws_size,
                              hipStream_t stream) {
    const float* x  = (const float*)d_in[0];
    float* out      = (float*)d_out;
    int nrows = in_sizes[0] / FDIM;                       // 32*4096 = 131072
    hipLaunchKernelGGL(comb_gather_kernel, dim3(GRID), dim3(BLOCK), 0, stream,
                       x, out, nrows);
}